// Round 12
// baseline (1032.707 us; speedup 1.0000x reference)
//
#include <hip/hip_runtime.h>

typedef unsigned char u8;
typedef unsigned int  u32;
using f32x4 = __attribute__((ext_vector_type(4))) float;

#define DI __device__ __forceinline__

// ---- fp8 e4m3 (OCP on gfx950) HW converts ----
DI u32 pk4f8(float a, float b, float c, float d){
  int w = __builtin_amdgcn_cvt_pk_fp8_f32(a, b, 0, false);
  w = __builtin_amdgcn_cvt_pk_fp8_f32(c, d, w, true);
  return (u32)w;
}
DI u8 enc1(float a){
  return (u8)(__builtin_amdgcn_cvt_pk_fp8_f32(a, a, 0, false) & 0xFF);
}
DI float dc0(u32 v){ return __builtin_amdgcn_cvt_f32_fp8((int)v, 0); }
DI float dc1(u32 v){ return __builtin_amdgcn_cvt_f32_fp8((int)v, 1); }
DI float dc2(u32 v){ return __builtin_amdgcn_cvt_f32_fp8((int)v, 2); }
DI float dc3(u32 v){ return __builtin_amdgcn_cvt_f32_fp8((int)v, 3); }

DI f32x4 MFMA8(long a, long b, f32x4 c){
  return __builtin_amdgcn_mfma_f32_16x16x32_fp8_fp8(a, b, c, 0, 0, 0);
}

// fp8 LDS tile: row stride 256 B; XOR swizzle
DI int swz8(int row, int col){ return (row << 8) + (col ^ ((row & 15) << 3)); }
DI long ldsA8(const u8* buf, int row, int k0){ return *(const long*)(buf + swz8(row, k0)); }
DI long ldG8(const u8* p){ return *(const long*)p; }

// fallback builders from f32 global (ws too small); scale ×8 like prep
DI long mk8(float v0, float v1, float v2, float v3, float v4, float v5, float v6, float v7){
  u32 lo = pk4f8(v0, v1, v2, v3), hi = pk4f8(v4, v5, v6, v7);
  return (long)(((unsigned long long)hi << 32) | (unsigned long long)lo);
}
DI long loadW8T(const float* __restrict__ W, int n, int k0){
  return mk8(W[(k0+0)*256+n]*8.f, W[(k0+1)*256+n]*8.f, W[(k0+2)*256+n]*8.f, W[(k0+3)*256+n]*8.f,
             W[(k0+4)*256+n]*8.f, W[(k0+5)*256+n]*8.f, W[(k0+6)*256+n]*8.f, W[(k0+7)*256+n]*8.f);
}
DI long loadW8T16(const float* __restrict__ W, int n, int k0){
  float v[8];
#pragma unroll
  for (int j = 0; j < 8; j++){ int k = k0 + j; v[j] = (k < 16) ? W[k*256+n]*8.f : 0.f; }
  return mk8(v[0],v[1],v[2],v[3],v[4],v[5],v[6],v[7]);
}
DI long loadW8row(const float* __restrict__ W, int n, int k0){
  const float* p = W + n*256 + k0;
  return mk8(p[0]*8.f,p[1]*8.f,p[2]*8.f,p[3]*8.f,p[4]*8.f,p[5]*8.f,p[6]*8.f,p[7]*8.f);
}

// d_ws layout (BYTE offsets), all weights fp8 e4m3, pre-scaled x8
#define WS_NEWT  0        // [256][32]  neW^T, K padded 16->32
#define WS_W1AT1 8192     // [256][256] g1W1[0:256]^T
#define WS_W1BT1 73728    // [256][256] g1W1[256:512]^T
#define WS_W2T1  139264   // [256][256] g1W2^T
#define WS_W1AT2 204800
#define WS_W1BT2 270336
#define WS_W2T2  335872
#define WS_PQWT  401408   // [256][256] pqW^T
#define WS_PKWP  466944   // [256][256] pkW plain copy
#define WS_TOTAL 532480

__global__ void prep_weights(
    const float* __restrict__ neW, const float* __restrict__ g1W1,
    const float* __restrict__ g1W2, const float* __restrict__ g2W1,
    const float* __restrict__ g2W2, const float* __restrict__ pqW,
    const float* __restrict__ pkW, u8* __restrict__ ws)
{
  int i = blockIdx.x * 256 + threadIdx.x;
  if (i >= WS_TOTAL) return;
  float v;
  if (i < 8192){
    int n = i >> 5, k = i & 31;
    v = (k < 16) ? neW[k * 256 + n] : 0.0f;
  } else {
    int j = i - 8192;
    int region = j >> 16;
    int idx = j & 65535;
    int n = idx >> 8, k = idx & 255;
    switch (region){
      case 0: v = g1W1[k * 256 + n]; break;
      case 1: v = g1W1[(256 + k) * 256 + n]; break;
      case 2: v = g1W2[k * 256 + n]; break;
      case 3: v = g2W1[k * 256 + n]; break;
      case 4: v = g2W1[(256 + k) * 256 + n]; break;
      case 5: v = g2W2[k * 256 + n]; break;
      case 6: v = pqW[k * 256 + n]; break;
      default: v = pkW[idx]; break;
    }
  }
  ws[i] = enc1(v * 8.0f);
}

// 1 workgroup = 4 batches = 80 rows. 512 threads = 8 waves; wave owns a
// 32-col N-slice (2 MFMA col-tiles). Rolled kk loops + 2-stage B prefetch.
// (512,4): cap 128 regs/wave, 2 blocks/CU = 4 waves/SIMD.
// Output f32: [oh B*8 | c1 B*10 | c2 B*10 | pl B*20].
template<bool PREPPED>
__global__ __launch_bounds__(512, 4) void fused_graphnet(
    const float* __restrict__ nf, const int* __restrict__ nn_c,
    const float* __restrict__ neW, const float* __restrict__ neb,
    const float* __restrict__ g1W1, const float* __restrict__ g1b1,
    const float* __restrict__ g1W2, const float* __restrict__ g1b2,
    const float* __restrict__ g2W1, const float* __restrict__ g2b1,
    const float* __restrict__ g2W2, const float* __restrict__ g2b2,
    const float* __restrict__ n1g, const float* __restrict__ n1b,
    const float* __restrict__ n2g, const float* __restrict__ n2b,
    const float* __restrict__ ohW, const float* __restrict__ ohb,
    const float* __restrict__ c1W, const float* __restrict__ c1b,
    const float* __restrict__ c2W, const float* __restrict__ c2b,
    const float* __restrict__ pqW, const float* __restrict__ pqb,
    const float* __restrict__ pkW, const float* __restrict__ pkb,
    const u8* __restrict__ ws, float* __restrict__ out,
    int out_n, int Bv)
{
  __shared__ __align__(16) u8 bufA[80 * 256];   // 20KB: h / pre-LN v (fp8)
  __shared__ __align__(16) u8 bufB[80 * 256];   // 20KB: nf then t1 (fp8)
  __shared__ __align__(16) u8 smallA[8 * 256];  // 2KB: msg/g rows 0..3, q rows 4..7
  __shared__ float pbf[4 * 256];                // pb then r (f32)
  __shared__ float rowstats[8][80][2];          // 5KB
  __shared__ float qdot[4];
  __shared__ int   cntS[4];
  __shared__ float dinvS[4];

  const int b0 = blockIdx.x * 4;
  const int tid = threadIdx.x;
  const int wave = tid >> 6, lane = tid & 63;
  const int lg = lane >> 4, lc = lane & 15;
  const int n0 = wave * 32;           // 32-col slice per wave

  const int Bout = out_n / 48;
  const int off_c1 = 8 * Bout;
  const int off_c2 = 18 * Bout;
  const int off_pl = 28 * Bout;

  if (tid < 4){
    int bi = b0 + tid; if (bi >= Bv) bi = Bv - 1;
    int c = nn_c[bi];
    c = c < 0 ? 0 : (c > 20 ? 20 : c);
    cntS[tid] = c;
    dinvS[tid] = 1.0f / (float)(c < 1 ? 1 : c);
  }

  // zero K-pad cols 16..31 of bufB; stage nf (fp8) into cols 0..15
  for (int i = tid; i < 80 * 4; i += 512){
    int row = i >> 2, c0 = 16 + (i & 3) * 4;
    *(u32*)(bufB + swz8(row, c0)) = 0u;
  }
  for (int i = tid; i < 80 * 4; i += 512){
    int row = i >> 2, k0 = (i & 3) * 4;
    int gr = b0 * 20 + row; if (gr >= Bv * 20) gr = Bv * 20 - 1;
    const float* p = nf + gr * 16 + k0;
    *(u32*)(bufB + swz8(row, k0)) = pk4f8(p[0], p[1], p[2], p[3]);
  }
  __syncthreads();   // S1

  const f32x4 zero4 = {0.0f, 0.0f, 0.0f, 0.0f};

  // GEMM0: h0 = nf @ neW + neb (single K-step of 32); A from bufB, h0 -> bufA
  {
    f32x4 acc[5][2];
#pragma unroll
    for (int mt = 0; mt < 5; mt++){
      long a = ldsA8(bufB, mt * 16 + lc, lg * 8);
#pragma unroll
      for (int nt = 0; nt < 2; nt++){
        int n = n0 + nt * 16 + lc;
        long bfr;
        if constexpr (PREPPED) bfr = ldG8(ws + WS_NEWT + n * 32 + lg * 8);
        else bfr = loadW8T16(neW, n, lg * 8);
        acc[mt][nt] = MFMA8(a, bfr, zero4);
      }
    }
#pragma unroll
    for (int nt = 0; nt < 2; nt++){
      float bb = neb[n0 + nt * 16 + lc];
#pragma unroll
      for (int mt = 0; mt < 5; mt++)
#pragma unroll
        for (int r = 0; r < 4; r++){
          int row = mt * 16 + lg * 4 + r;
          int col = n0 + nt * 16 + lc;
          bufA[swz8(row, col)] = enc1(acc[mt][nt][r] * 0.125f + bb);
        }
    }
  }
  __syncthreads();   // S2

  for (int rd = 0; rd < 2; rd++){
    const int w1at = (rd == 0) ? WS_W1AT1 : WS_W1AT2;
    const int w1bt = (rd == 0) ? WS_W1BT1 : WS_W1BT2;
    const int w2t  = (rd == 0) ? WS_W2T1  : WS_W2T2;
    const float* W1 = (rd == 0) ? g1W1 : g2W1;
    const float* W2 = (rd == 0) ? g1W2 : g2W2;
    const float* b1p = (rd == 0) ? g1b1 : g2b1;
    const float* b2p = (rd == 0) ? g1b2 : g2b2;
    const float* ngp = (rd == 0) ? n1g : n2g;
    const float* nbp = (rd == 0) ? n1b : n2b;

    // masked mean of h (bufA) -> smallA rows 0..3 (first 256 threads)
    if (tid < 256){
      int b = tid >> 6;
      int c0 = (tid & 63) * 4;
      int c = cntS[b];
      float s0 = 0, s1 = 0, s2 = 0, s3 = 0;
      for (int r = 0; r < c; r++){
        u32 v = *(const u32*)(bufA + swz8(b * 20 + r, c0));
        s0 += dc0(v); s1 += dc1(v); s2 += dc2(v); s3 += dc3(v);
      }
      float di = dinvS[b];
      *(u32*)(smallA + swz8(b, c0)) = pk4f8(s0 * di, s1 * di, s2 * di, s3 * di);
    }
    __syncthreads();   // S3

    // pb = msg @ W1b + b1 -> pbf (lg==0, own 32 cols); prefetched rolled kk
    {
      f32x4 acc[2];
#pragma unroll
      for (int nt = 0; nt < 2; nt++) acc[nt] = zero4;
      long bp0, bp1;
      {
        int n_0 = n0 + lc, n_1 = n0 + 16 + lc;
        if constexpr (PREPPED){ bp0 = ldG8(ws + w1bt + n_0 * 256 + lg * 8); bp1 = ldG8(ws + w1bt + n_1 * 256 + lg * 8); }
        else { bp0 = loadW8T(W1 + 256 * 256, n_0, lg * 8); bp1 = loadW8T(W1 + 256 * 256, n_1, lg * 8); }
      }
#pragma unroll 1
      for (int kk = 0; kk < 8; kk++){
        long bn0 = bp0, bn1 = bp1;
        if (kk < 7){
          int k1 = (kk + 1) * 32 + lg * 8;
          int n_0 = n0 + lc, n_1 = n0 + 16 + lc;
          if constexpr (PREPPED){ bp0 = ldG8(ws + w1bt + n_0 * 256 + k1); bp1 = ldG8(ws + w1bt + n_1 * 256 + k1); }
          else { bp0 = loadW8T(W1 + 256 * 256, n_0, k1); bp1 = loadW8T(W1 + 256 * 256, n_1, k1); }
        }
        long a = ldsA8(smallA, lc & 3, kk * 32 + lg * 8);
        acc[0] = MFMA8(a, bn0, acc[0]);
        acc[1] = MFMA8(a, bn1, acc[1]);
      }
      if (lg == 0){
#pragma unroll
        for (int nt = 0; nt < 2; nt++)
#pragma unroll
          for (int r = 0; r < 4; r++){
            int col = n0 + nt * 16 + lc;
            pbf[r * 256 + col] = acc[nt][r] * 0.125f + b1p[col];
          }
      }
    }

    // G1: t1 = relu(h @ W1a * 0.125 + pb) -> bufB; prefetched rolled kk
    {
      f32x4 tacc[5][2];
#pragma unroll
      for (int mt = 0; mt < 5; mt++)
#pragma unroll
        for (int nt = 0; nt < 2; nt++) tacc[mt][nt] = zero4;
      long bp0, bp1;
      {
        int n_0 = n0 + lc, n_1 = n0 + 16 + lc;
        if constexpr (PREPPED){ bp0 = ldG8(ws + w1at + n_0 * 256 + lg * 8); bp1 = ldG8(ws + w1at + n_1 * 256 + lg * 8); }
        else { bp0 = loadW8T(W1, n_0, lg * 8); bp1 = loadW8T(W1, n_1, lg * 8); }
      }
#pragma unroll 1
      for (int kk = 0; kk < 8; kk++){
        long bn0 = bp0, bn1 = bp1;
        if (kk < 7){
          int k1 = (kk + 1) * 32 + lg * 8;
          int n_0 = n0 + lc, n_1 = n0 + 16 + lc;
          if constexpr (PREPPED){ bp0 = ldG8(ws + w1at + n_0 * 256 + k1); bp1 = ldG8(ws + w1at + n_1 * 256 + k1); }
          else { bp0 = loadW8T(W1, n_0, k1); bp1 = loadW8T(W1, n_1, k1); }
        }
#pragma unroll
        for (int mt = 0; mt < 5; mt++){
          long a = ldsA8(bufA, mt * 16 + lc, kk * 32 + lg * 8);
          tacc[mt][0] = MFMA8(a, bn0, tacc[mt][0]);
          tacc[mt][1] = MFMA8(a, bn1, tacc[mt][1]);
        }
      }
#pragma unroll
      for (int mt = 0; mt < 5; mt++)
#pragma unroll
        for (int nt = 0; nt < 2; nt++)
#pragma unroll
          for (int r = 0; r < 4; r++){
            int row = mt * 16 + lg * 4 + r;
            int col = n0 + nt * 16 + lc;
            float v = tacc[mt][nt][r] * 0.125f + pbf[(row / 20) * 256 + col];
            bufB[swz8(row, col)] = enc1(fmaxf(v, 0.0f));
          }
    }
    __syncthreads();   // S4: t1 visible; all G1 h-reads done

    // G2: v = t1 @ W2 * 0.125 + residual(bufA) + b2 -> bufA (own cols, pre-LN)
    {
      f32x4 tacc[5][2];
#pragma unroll
      for (int mt = 0; mt < 5; mt++)
#pragma unroll
        for (int nt = 0; nt < 2; nt++) tacc[mt][nt] = zero4;
      long bp0, bp1;
      {
        int n_0 = n0 + lc, n_1 = n0 + 16 + lc;
        if constexpr (PREPPED){ bp0 = ldG8(ws + w2t + n_0 * 256 + lg * 8); bp1 = ldG8(ws + w2t + n_1 * 256 + lg * 8); }
        else { bp0 = loadW8T(W2, n_0, lg * 8); bp1 = loadW8T(W2, n_1, lg * 8); }
      }
#pragma unroll 1
      for (int kk = 0; kk < 8; kk++){
        long bn0 = bp0, bn1 = bp1;
        if (kk < 7){
          int k1 = (kk + 1) * 32 + lg * 8;
          int n_0 = n0 + lc, n_1 = n0 + 16 + lc;
          if constexpr (PREPPED){ bp0 = ldG8(ws + w2t + n_0 * 256 + k1); bp1 = ldG8(ws + w2t + n_1 * 256 + k1); }
          else { bp0 = loadW8T(W2, n_0, k1); bp1 = loadW8T(W2, n_1, k1); }
        }
#pragma unroll
        for (int mt = 0; mt < 5; mt++){
          long a = ldsA8(bufB, mt * 16 + lc, kk * 32 + lg * 8);
          tacc[mt][0] = MFMA8(a, bn0, tacc[mt][0]);
          tacc[mt][1] = MFMA8(a, bn1, tacc[mt][1]);
        }
      }
#pragma unroll
      for (int nt = 0; nt < 2; nt++){
        float b2s = b2p[n0 + nt * 16 + lc];
#pragma unroll
        for (int mt = 0; mt < 5; mt++)
#pragma unroll
          for (int r = 0; r < 4; r++){
            int row = mt * 16 + lg * 4 + r;
            int col = n0 + nt * 16 + lc;
            u32 rv = bufA[swz8(row, col)];              // residual (same thread wrote it)
            float v = tacc[mt][nt][r] * 0.125f + dc0(rv) + b2s;
            bufA[swz8(row, col)] = enc1(v);             // pre-LN v, own cols
          }
      }
    }

    // LN: stats from bufA (own cols); then normalize
    {
#pragma unroll
      for (int mt = 0; mt < 5; mt++)
#pragma unroll
        for (int r = 0; r < 4; r++){
          int row = mt * 16 + lg * 4 + r;
          float s1 = 0, s2 = 0;
#pragma unroll
          for (int nt = 0; nt < 2; nt++){
            float v = dc0((u32)bufA[swz8(row, n0 + nt * 16 + lc)]);
            s1 += v; s2 += v * v;
          }
#pragma unroll
          for (int d = 1; d < 16; d <<= 1){ s1 += __shfl_xor(s1, d, 64); s2 += __shfl_xor(s2, d, 64); }
          if (lc == 0){ rowstats[wave][row][0] = s1; rowstats[wave][row][1] = s2; }
        }
      __syncthreads();   // S5

#pragma unroll
      for (int mt = 0; mt < 5; mt++)
#pragma unroll
        for (int r = 0; r < 4; r++){
          int row = mt * 16 + lg * 4 + r;
          float t1s = 0, t2s = 0;
#pragma unroll
          for (int w = 0; w < 8; w++){ t1s += rowstats[w][row][0]; t2s += rowstats[w][row][1]; }
          float mean = t1s * (1.0f / 256.0f);
          float var  = t2s * (1.0f / 256.0f) - mean * mean;
          float rstd = rsqrtf(fmaxf(var, 0.0f) + 1e-5f);
          int bb = row / 20;
          float mf = ((row - bb * 20) < cntS[bb]) ? 1.0f : 0.0f;
#pragma unroll
          for (int nt = 0; nt < 2; nt++){
            int col = n0 + nt * 16 + lc;
            float v = dc0((u32)bufA[swz8(row, col)]);
            bufA[swz8(row, col)] = enc1(((v - mean) * rstd * ngp[col] + nbp[col]) * mf);
          }
        }
    }
    __syncthreads();   // S6
  }

  // g = masked mean -> smallA rows 0..3 (first 256 threads)
  if (tid < 256){
    int b = tid >> 6;
    int c0 = (tid & 63) * 4;
    int c = cntS[b];
    float s0 = 0, s1 = 0, s2 = 0, s3 = 0;
    for (int r = 0; r < c; r++){
      u32 v = *(const u32*)(bufA + swz8(b * 20 + r, c0));
      s0 += dc0(v); s1 += dc1(v); s2 += dc2(v); s3 += dc3(v);
    }
    float di = dinvS[b];
    *(u32*)(smallA + swz8(b, c0)) = pk4f8(s0 * di, s1 * di, s2 * di, s3 * di);
  }
  __syncthreads();   // S7

  // q = g @ pqW + pqb -> smallA rows 4..7
  {
    f32x4 qacc[2];
#pragma unroll
    for (int nt = 0; nt < 2; nt++) qacc[nt] = zero4;
#pragma unroll 1
    for (int kk = 0; kk < 8; kk++){
      long a = ldsA8(smallA, lc & 3, kk * 32 + lg * 8);
#pragma unroll
      for (int nt = 0; nt < 2; nt++){
        int n = n0 + nt * 16 + lc;
        long bfr;
        if constexpr (PREPPED) bfr = ldG8(ws + WS_PQWT + n * 256 + kk * 32 + lg * 8);
        else bfr = loadW8T(pqW, n, kk * 32 + lg * 8);
        qacc[nt] = MFMA8(a, bfr, qacc[nt]);
      }
    }
    if (lg == 0){
#pragma unroll
      for (int nt = 0; nt < 2; nt++)
#pragma unroll
        for (int r = 0; r < 4; r++){
          int col = n0 + nt * 16 + lc;
          smallA[swz8(4 + r, col)] = enc1(qacc[nt][r] * 0.125f + pqb[col]);
        }
    }
  }
  __syncthreads();   // S8

  // qdot[b] = q[b].pkb (waves 0..3, batch = wave)
  if (wave < 4){
    u32 qv = *(const u32*)(smallA + swz8(4 + wave, lane * 4));
    float p = dc0(qv) * pkb[lane * 4 + 0] + dc1(qv) * pkb[lane * 4 + 1]
            + dc2(qv) * pkb[lane * 4 + 2] + dc3(qv) * pkb[lane * 4 + 3];
#pragma unroll
    for (int d = 1; d < 64; d <<= 1) p += __shfl_xor(p, d, 64);
    if (lane == 0) qdot[wave] = p;
  }

  // r[b][n] = sum_k q[b][k]*pkW[n][k] -> pbf
  {
    f32x4 racc[2];
#pragma unroll
    for (int nt = 0; nt < 2; nt++) racc[nt] = zero4;
#pragma unroll 1
    for (int kk = 0; kk < 8; kk++){
      long a = ldsA8(smallA, 4 + (lc & 3), kk * 32 + lg * 8);
#pragma unroll
      for (int nt = 0; nt < 2; nt++){
        int n = n0 + nt * 16 + lc;
        long bfr;
        if constexpr (PREPPED) bfr = ldG8(ws + WS_PKWP + n * 256 + kk * 32 + lg * 8);
        else bfr = loadW8row(pkW, n, kk * 32 + lg * 8);
        racc[nt] = MFMA8(a, bfr, racc[nt]);
      }
    }
    if (lg == 0){
#pragma unroll
      for (int nt = 0; nt < 2; nt++)
#pragma unroll
        for (int r = 0; r < 4; r++)
          pbf[r * 256 + (n0 + nt * 16 + lc)] = racc[nt][r] * 0.125f;
    }
  }
  __syncthreads();   // S9

  // pl (waves 0..3, batch = wave) ; heads (waves 4..7, batch = wave-4)
  if (wave < 4){
    const int b = wave;
    if (b0 + b < Bv){
      int cb = cntS[b];
      float qd = qdot[b];
      for (int rr = 0; rr < 20; rr++){
        int row = b * 20 + rr;
        u32 hv = *(const u32*)(bufA + swz8(row, lane * 4));
        const float* rp = pbf + b * 256 + lane * 4;
        float p = dc0(hv) * rp[0] + dc1(hv) * rp[1] + dc2(hv) * rp[2] + dc3(hv) * rp[3];
#pragma unroll
        for (int d = 1; d < 64; d <<= 1) p += __shfl_xor(p, d, 64);
        if (lane == 0){
          float v = (rr < cb) ? (p + qd) : -1e9f;
          out[off_pl + (b0 + b) * 20 + rr] = v;
        }
      }
    }
  } else {
    const int b = wave - 4;
    if (b0 + b < Bv){
      u32 gv = *(const u32*)(smallA + swz8(b, lane * 4));
      float g0 = dc0(gv), g1 = dc1(gv), g2 = dc2(gv), g3 = dc3(gv);
#pragma unroll 1
      for (int o = 0; o < 28; o++){
        const float* W; const float* bias; int ncol, col, off;
        if (o < 8)      { W = ohW; bias = ohb; ncol = 8;  col = o;      off = 0; }
        else if (o < 18){ W = c1W; bias = c1b; ncol = 10; col = o - 8;  off = off_c1; }
        else            { W = c2W; bias = c2b; ncol = 10; col = o - 18; off = off_c2; }
        int k = lane * 4;
        float p = g0 * W[(k + 0) * ncol + col] + g1 * W[(k + 1) * ncol + col]
                + g2 * W[(k + 2) * ncol + col] + g3 * W[(k + 3) * ncol + col];
#pragma unroll
        for (int d = 1; d < 64; d <<= 1) p += __shfl_xor(p, d, 64);
        if (lane == 0) out[off + (b0 + b) * ncol + col] = p + bias[col];
      }
    }
  }
}

extern "C" void kernel_launch(void* const* d_in, const int* in_sizes, int n_in,
                              void* d_out, int out_size, void* d_ws, size_t ws_size,
                              hipStream_t stream)
{
  const float* nf   = (const float*)d_in[0];
  const int*   nn_c = (const int*)d_in[1];
  const float* neW  = (const float*)d_in[2];
  const float* neb  = (const float*)d_in[3];
  const float* g1W1 = (const float*)d_in[4];
  const float* g1b1 = (const float*)d_in[5];
  const float* g1W2 = (const float*)d_in[6];
  const float* g1b2 = (const float*)d_in[7];
  const float* g2W1 = (const float*)d_in[8];
  const float* g2b1 = (const float*)d_in[9];
  const float* g2W2 = (const float*)d_in[10];
  const float* g2b2 = (const float*)d_in[11];
  const float* n1g  = (const float*)d_in[12];
  const float* n1b  = (const float*)d_in[13];
  const float* n2g  = (const float*)d_in[14];
  const float* n2b  = (const float*)d_in[15];
  const float* ohW  = (const float*)d_in[16];
  const float* ohb  = (const float*)d_in[17];
  const float* c1W  = (const float*)d_in[18];
  const float* c1b  = (const float*)d_in[19];
  const float* c2W  = (const float*)d_in[20];
  const float* c2b  = (const float*)d_in[21];
  const float* pqW  = (const float*)d_in[22];
  const float* pqb  = (const float*)d_in[23];
  const float* pkW  = (const float*)d_in[24];
  const float* pkb  = (const float*)d_in[25];

  float* outp = (float*)d_out;
  u8* ws = (u8*)d_ws;
  int B = in_sizes[0] / 320;       // nf is [B,20,16]
  int grid = (B + 3) / 4;

  if (ws_size >= (size_t)WS_TOTAL){
    prep_weights<<<(WS_TOTAL + 255) / 256, 256, 0, stream>>>(
        neW, g1W1, g1W2, g2W1, g2W2, pqW, pkW, ws);
    fused_graphnet<true><<<grid, 512, 0, stream>>>(
        nf, nn_c, neW, neb, g1W1, g1b1, g1W2, g1b2, g2W1, g2b1, g2W2, g2b2,
        n1g, n1b, n2g, n2b, ohW, ohb, c1W, c1b, c2W, c2b, pqW, pqb, pkW, pkb,
        ws, outp, out_size, B);
  } else {
    fused_graphnet<false><<<grid, 512, 0, stream>>>(
        nf, nn_c, neW, neb, g1W1, g1b1, g1W2, g1b2, g2W1, g2b1, g2W2, g2b2,
        n1g, n1b, n2g, n2b, ohW, ohb, c1W, c1b, c2W, c2b, pqW, pqb, pkW, pkb,
        ws, outp, out_size, B);
  }
}